// Round 15
// baseline (206.949 us; speedup 1.0000x reference)
//
#include <hip/hip_runtime.h>

#define D_MODEL 1024
#define HEADS   16
#define HEAD_DIM 64
#define SEQ     2048
#define BATCH   2
#define ROWS    (BATCH*SEQ)   /* 4096 */
#define FFDIM   4096

typedef __attribute__((ext_vector_type(8))) short short8;
typedef __attribute__((ext_vector_type(4))) float f32x4;
typedef __attribute__((ext_vector_type(4))) unsigned short us4;

typedef const __attribute__((address_space(1))) unsigned int* gptr_t;
typedef __attribute__((address_space(3))) unsigned int* lptr_t;

__device__ __forceinline__ unsigned short f2bf(float f){
  unsigned int x = __float_as_uint(f);
  x += 0x7fffu + ((x >> 16) & 1u);
  return (unsigned short)(x >> 16);
}
__device__ __forceinline__ float bf2f(unsigned short u){
  return __uint_as_float((unsigned int)u << 16);
}

__device__ __forceinline__ float wave_sum(float x){
  #pragma unroll
  for (int off = 32; off; off >>= 1) x += __shfl_xor(x, off);
  return x;
}

// ---------------- cast fp32 -> bf16 (vectorized) ----------------
__global__ __launch_bounds__(256) void cast_bf16_kernel(const float* __restrict__ in,
                                                        unsigned short* __restrict__ out, int n4){
  int i = blockIdx.x * 256 + threadIdx.x;
  if (i >= n4) return;
  float4 v = *(const float4*)(in + (size_t)i * 4);
  us4 o;
  o[0] = f2bf(v.x); o[1] = f2bf(v.y); o[2] = f2bf(v.z); o[3] = f2bf(v.w);
  *(us4*)(out + (size_t)i * 4) = o;
}

// ---------------- transpose + cast: in [R][C] f32 -> out [C][R] bf16 ----------------
__global__ __launch_bounds__(256) void transpose_cast_kernel(const float* __restrict__ in,
                                                             unsigned short* __restrict__ out,
                                                             int R, int C){
  __shared__ float tile[32][33];
  const int bc = blockIdx.x * 32, br = blockIdx.y * 32;
  const int tx = threadIdx.x & 31, ty = threadIdx.x >> 5;  // ty 0..7
  #pragma unroll
  for (int j = 0; j < 4; ++j)
    tile[ty + 8*j][tx] = in[(size_t)(br + ty + 8*j) * C + bc + tx];
  __syncthreads();
  #pragma unroll
  for (int j = 0; j < 4; ++j)
    out[(size_t)(bc + ty + 8*j) * R + br + tx] = f2bf(tile[tx][ty + 8*j]);
}

// ---------------- bf16 MFMA GEMM v2 (proven): 2-phase dbuf, XCD-swizzled ----------------
// EPI 0: QKV epilogue -> q bf16 (scaled 0.125*log2e), k bf16, V^T bf16 [B,H,64,T]
// EPI 3: f32 partial (no bias) to outF + sk*M*N   (split-K fallback)
template<int EPI>
__global__ __launch_bounds__(256) void gemm_kernel(const unsigned short* __restrict__ A,
                                                   const unsigned short* __restrict__ BT,
                                                   const float* __restrict__ bias,
                                                   int M, int N, int K, int kchunk,
                                                   int gx, int gy,
                                                   float* __restrict__ outF,
                                                   unsigned short* __restrict__ qo,
                                                   unsigned short* __restrict__ ko,
                                                   unsigned short* __restrict__ vT){
  __shared__ __align__(16) unsigned short Alds[2][128 * 32];
  __shared__ __align__(16) unsigned short Blds[2][128 * 32];
  const int tid = threadIdx.x;
  const int lane = tid & 63;
  const int wid = tid >> 6;
  const int wr = wid >> 1, wc = wid & 1;
  const int lrow = lane & 15, lgrp = lane >> 4;

  const int nwg = gridDim.x;
  const int cpx = nwg >> 3;
  const int wg = (blockIdx.x & 7) * cpx + (blockIdx.x >> 3);
  const int nx = wg % gx;
  const int rest = wg / gx;
  const int my = rest % gy;
  const int sk = rest / gy;

  const int m0 = my * 128, n0 = nx * 128;
  const int kbase0 = sk * kchunk;
  const int sr = lane >> 2, sc = (lane & 3) * 8;

  f32x4 acc[4][4];
  #pragma unroll
  for (int i = 0; i < 4; ++i)
    #pragma unroll
    for (int j = 0; j < 4; ++j)
      acc[i][j] = f32x4{0.f, 0.f, 0.f, 0.f};

  #pragma unroll
  for (int it = 0; it < 2; ++it){
    const int c = wid * 2 + it;
    const int r = c * 16 + sr;
    __builtin_amdgcn_global_load_lds(
        (gptr_t)(const void*)(A + (size_t)(m0 + r) * K + kbase0 + sc),
        (lptr_t)(void*)(&Alds[0][c * 512]), 16, 0, 0);
    __builtin_amdgcn_global_load_lds(
        (gptr_t)(const void*)(BT + (size_t)(n0 + r) * K + kbase0 + sc),
        (lptr_t)(void*)(&Blds[0][c * 512]), 16, 0, 0);
  }

  const int nk = kchunk >> 5;
  int cur = 0;
  for (int kt = 0; kt < nk; ++kt){
    __syncthreads();
    if (kt + 1 < nk){
      const int kb = kbase0 + (kt + 1) * 32;
      #pragma unroll
      for (int it = 0; it < 2; ++it){
        const int c = wid * 2 + it;
        const int r = c * 16 + sr;
        __builtin_amdgcn_global_load_lds(
            (gptr_t)(const void*)(A + (size_t)(m0 + r) * K + kb + sc),
            (lptr_t)(void*)(&Alds[cur ^ 1][c * 512]), 16, 0, 0);
        __builtin_amdgcn_global_load_lds(
            (gptr_t)(const void*)(BT + (size_t)(n0 + r) * K + kb + sc),
            (lptr_t)(void*)(&Blds[cur ^ 1][c * 512]), 16, 0, 0);
      }
    }
    short8 af[4], bfr[4];
    #pragma unroll
    for (int f = 0; f < 4; ++f){
      af[f]  = *(const short8*)&Alds[cur][(wr * 64 + f * 16 + lrow) * 32 + lgrp * 8];
      bfr[f] = *(const short8*)&Blds[cur][(wc * 64 + f * 16 + lrow) * 32 + lgrp * 8];
    }
    __builtin_amdgcn_s_setprio(1);
    #pragma unroll
    for (int i = 0; i < 4; ++i)
      #pragma unroll
      for (int j = 0; j < 4; ++j)
        acc[i][j] = __builtin_amdgcn_mfma_f32_16x16x32_bf16(af[i], bfr[j], acc[i][j], 0, 0, 0);
    __builtin_amdgcn_s_setprio(0);
    cur ^= 1;
  }

  // epilogue: D row = (lane>>4)*4 + reg, col = lane&15 (m89-verified layout)
  #pragma unroll
  for (int i = 0; i < 4; ++i){
    const int rg = m0 + wr * 64 + i * 16 + lgrp * 4;
    #pragma unroll
    for (int j = 0; j < 4; ++j){
      const int cg = n0 + wc * 64 + j * 16 + lrow;
      if constexpr (EPI == 0){
        const float bb = bias[cg];
        const int which = cg >> 10, rem = cg & 1023;
        const int hh = rem >> 6, dd = rem & 63;
        const int bb_ = rg >> 11, tt = rg & 2047;
        const size_t bh = (size_t)(bb_ * HEADS + hh);
        if (which == 2){
          us4 pk;
          #pragma unroll
          for (int r = 0; r < 4; ++r) pk[r] = f2bf(acc[i][j][r] + bb);
          *(us4*)(vT + (bh * 64 + dd) * SEQ + tt) = pk;
        } else {
          unsigned short* dst = which ? ko : qo;
          const float sc2 = which ? 1.0f : 0.18033688f;  // q: (1/8)*log2e
          #pragma unroll
          for (int r = 0; r < 4; ++r)
            dst[(bh * SEQ + tt + r) * 64 + dd] = f2bf((acc[i][j][r] + bb) * sc2);
        }
      } else {
        float* outP = outF + (size_t)sk * M * N;
        #pragma unroll
        for (int r = 0; r < 4; ++r)
          outP[(size_t)(rg + r) * N + cg] = acc[i][j][r];
      }
    }
  }
}

// ================= 256x256 4-barrier-halved bf16 MFMA GEMM ("gemm4b") =================
// (proven r14 schedule — unchanged)
template<int EPI>
__global__ __launch_bounds__(512, 1) void gemm4b_kernel(const unsigned short* __restrict__ A,
                                                        const unsigned short* __restrict__ BT,
                                                        const float* __restrict__ bias,
                                                        int M, int N, int K, int kchunk,
                                                        int gx, int gy,
                                                        unsigned short* __restrict__ outH){
  __shared__ __align__(16) unsigned short Ab[2][2][256 * 32];
  __shared__ __align__(16) unsigned short Bb[2][2][256 * 32];
  const int tid = threadIdx.x, lane = tid & 63, wid = tid >> 6;
  const int wm = wid >> 2, wn = wid & 3;
  const int lr = lane & 15, g = lane >> 4;

  const int nwg = gridDim.x, cpx = nwg >> 3;
  const int wg = (blockIdx.x & 7) * cpx + (blockIdx.x >> 3);
  const int nx = wg % gx;
  const int rest = wg / gx;
  const int my = rest % gy;
  const int sk = rest / gy;
  const int m0 = my * 256, n0 = nx * 256, kb0 = sk * kchunk;
  const int nk = kchunk >> 6;   // BK = 64

  f32x4 acc[8][4];
  #pragma unroll
  for (int i = 0; i < 8; ++i)
    #pragma unroll
    for (int j = 0; j < 4; ++j)
      acc[i][j] = f32x4{0.f, 0.f, 0.f, 0.f};

  auto STAGE = [&](int op, int t, int kh){
    const int d_ = t & 1;
    unsigned short* base = op ? &Bb[d_][kh][0] : &Ab[d_][kh][0];
    const unsigned short* src = op ? BT : A;
    const int r0 = op ? n0 : m0;
    #pragma unroll
    for (int j = 0; j < 2; ++j){
      const int L = tid + j * 512;
      const int row = L >> 2, c = L & 3;
      __builtin_amdgcn_global_load_lds(
          (gptr_t)(const void*)(src + (size_t)(r0 + row) * K + kb0 + t * 64 + kh * 32
                                + ((c ^ ((row >> 1) & 3)) << 3)),
          (lptr_t)(void*)(base + L * 8), 16, 0, 0);
    }
  };

  short8 afr[8], bfr[4];

  #define READS(d_, kh_)                                                                  \
    _Pragma("unroll")                                                                     \
    for (int i = 0; i < 8; ++i){                                                          \
      const int row = wm * 128 + i * 16 + lr;                                             \
      afr[i] = *(const short8*)&Ab[d_][kh_][row * 32 + ((g ^ ((row >> 1) & 3)) << 3)];    \
    }                                                                                     \
    _Pragma("unroll")                                                                     \
    for (int j = 0; j < 4; ++j){                                                          \
      const int row = wn * 64 + j * 16 + lr;                                              \
      bfr[j] = *(const short8*)&Bb[d_][kh_][row * 32 + ((g ^ ((row >> 1) & 3)) << 3)];    \
    }

  #define MFMA32()                                                                        \
    __builtin_amdgcn_sched_barrier(0);                                                    \
    __builtin_amdgcn_s_setprio(1);                                                        \
    _Pragma("unroll")                                                                     \
    for (int i = 0; i < 8; ++i)                                                           \
      _Pragma("unroll")                                                                   \
      for (int j = 0; j < 4; ++j)                                                         \
        acc[i][j] = __builtin_amdgcn_mfma_f32_16x16x32_bf16(afr[i], bfr[j], acc[i][j], 0, 0, 0); \
    __builtin_amdgcn_s_setprio(0);

  // prologue: stage (0,kh0), (0,kh1), (1,kh0)
  STAGE(0,0,0); STAGE(1,0,0); STAGE(0,0,1); STAGE(1,0,1);
  if (nk > 1){ STAGE(0,1,0); STAGE(1,1,0); }

  for (int t = 0; t < nk; ++t){
    const int d = t & 1;

    // ---- Phase A(t): consume (t,kh0) ----
    if (t + 1 < nk) asm volatile("s_waitcnt vmcnt(8)" ::: "memory");
    else            asm volatile("s_waitcnt vmcnt(4)" ::: "memory");
    __builtin_amdgcn_s_barrier();
    READS(d, 0)
    if (t + 1 < nk){ STAGE(0, t + 1, 1); STAGE(1, t + 1, 1); }
    asm volatile("s_waitcnt lgkmcnt(0)" ::: "memory");
    MFMA32()

    // ---- Phase B(t): consume (t,kh1) ----
    if (t + 1 < nk) asm volatile("s_waitcnt vmcnt(8)" ::: "memory");
    else            asm volatile("s_waitcnt vmcnt(0)" ::: "memory");
    __builtin_amdgcn_s_barrier();
    READS(d, 1)
    if (t + 2 < nk){ STAGE(0, t + 2, 0); STAGE(1, t + 2, 0); }
    asm volatile("s_waitcnt lgkmcnt(0)" ::: "memory");
    MFMA32()
  }
  #undef READS
  #undef MFMA32

  // ---- epilogue: D row = g*4 + reg, col = lr (m89-verified) ----
  #pragma unroll
  for (int i = 0; i < 8; ++i){
    const int rg = m0 + wm * 128 + i * 16 + g * 4;
    #pragma unroll
    for (int j = 0; j < 4; ++j){
      const int cg = n0 + wn * 64 + j * 16 + lr;
      if constexpr (EPI == 1){
        const float bb = bias[cg];
        #pragma unroll
        for (int r = 0; r < 4; ++r)
          outH[(size_t)(rg + r) * N + cg] = f2bf(fmaxf(acc[i][j][r] + bb, 0.f));
      } else {
        unsigned short* dst = outH + (size_t)sk * M * N;
        #pragma unroll
        for (int r = 0; r < 4; ++r)
          dst[(size_t)(rg + r) * N + cg] = f2bf(acc[i][j][r]);
      }
    }
  }
}

// ---------------- MFMA flash attention v4: K in LDS, V direct from global (L2) ----------
// Per XCD only ~4 heads' K/V (~2MB) live -> L2-resident; V fragments are 16B-contiguous
// global reads issued right after the K-tile barrier (BEFORE the K-prefetch loads, so
// waiting on V never drains the prefetch); latency hides under QK+softmax.
__global__ __launch_bounds__(256) void attn_mfma_kernel(const unsigned short* __restrict__ Qb,
                                                        const unsigned short* __restrict__ Kb,
                                                        const unsigned short* __restrict__ VT,
                                                        float* __restrict__ Op){
  __shared__ __align__(16) char Kl[2][8192];
  __shared__ __align__(16) char Pl[4][4096];
  const int tid = threadIdx.x;
  const int w = tid >> 6, lane = tid & 63;
  const int lr = lane & 15, g = lane >> 4;

  const int bx = blockIdx.x, u = bx & 255, half = bx >> 8;
  const int g8 = u >> 5;
  const int qg = half ? g8 : 15 - g8;
  const int bh = u & 31;

  const int q0w = qg * 128 + w * 32;
  const int qA = q0w + lr, qB = qA + 16;

  const char* const KbB = (const char*)(Kb + (size_t)bh * SEQ * 64);
  const unsigned short* const Vg = VT + (size_t)bh * 64 * SEQ;
  char* const PbA = Pl[w];
  char* const PbB = Pl[w] + 2048;

  const unsigned short* qra = Qb + ((size_t)bh * SEQ + qA) * 64 + g * 8;
  const short8 qfA0 = *(const short8*)(qra);
  const short8 qfA1 = *(const short8*)(qra + 32);
  const short8 qfB0 = *(const short8*)(qra + 16 * 64);
  const short8 qfB1 = *(const short8*)(qra + 16 * 64 + 32);

  f32x4 oA[4], oB[4];
  #pragma unroll
  for (int dt = 0; dt < 4; ++dt){ oA[dt] = f32x4{0.f,0.f,0.f,0.f}; oB[dt] = f32x4{0.f,0.f,0.f,0.f}; }
  float lA = 0.f, lB = 0.f;
  const int swzl = (lr & 7) << 4;

  const int kbmax = 2 * qg + 1;

  short8 st[2];
  {
    #pragma unroll
    for (int c = 0; c < 2; ++c)
      st[c] = *(const short8*)(KbB + c * 4096 + tid * 16);
  }

  for (int kb = 0; kb <= kbmax; ++kb){
    const int p = kb & 1;
    const int k0 = kb * 64;

    #pragma unroll
    for (int c = 0; c < 2; ++c){
      const int L = c * 4096 + tid * 16;
      const int row = L >> 7, col = L & 127;
      *(short8*)(Kl[p] + row * 128 + (col ^ ((row & 7) << 4))) = st[c];
    }
    __syncthreads();

    // ---- V direct loads for this tile (issued first: oldest in vm queue) ----
    short8 vf[4][2];
    #pragma unroll
    for (int dt = 0; dt < 4; ++dt){
      const unsigned short* vrow = Vg + (size_t)(dt * 16 + lr) * SEQ + k0 + g * 8;
      vf[dt][0] = *(const short8*)(vrow);
      vf[dt][1] = *(const short8*)(vrow + 32);
    }

    f32x4 sA[4], sB[4];
    __builtin_amdgcn_s_setprio(1);
    #pragma unroll
    for (int kt = 0; kt < 4; ++kt){
      const int row = kt * 16 + lr;
      const int ro = row * 128, sw = (row & 7) << 4;
      const short8 kf0 = *(const short8*)(Kl[p] + ro + ((g * 16) ^ sw));
      const short8 kf1 = *(const short8*)(Kl[p] + ro + ((64 + g * 16) ^ sw));
      sA[kt] = __builtin_amdgcn_mfma_f32_16x16x32_bf16(kf0, qfA0, f32x4{0.f,0.f,0.f,0.f}, 0, 0, 0);
      sA[kt] = __builtin_amdgcn_mfma_f32_16x16x32_bf16(kf1, qfA1, sA[kt], 0, 0, 0);
      sB[kt] = __builtin_amdgcn_mfma_f32_16x16x32_bf16(kf0, qfB0, f32x4{0.f,0.f,0.f,0.f}, 0, 0, 0);
      sB[kt] = __builtin_amdgcn_mfma_f32_16x16x32_bf16(kf1, qfB1, sB[kt], 0, 0, 0);
    }
    __builtin_amdgcn_s_setprio(0);

    // ---- K prefetch for next tile (after V loads: newer in vm queue) ----
    if (kb < kbmax){
      #pragma unroll
      for (int c = 0; c < 2; ++c)
        st[c] = *(const short8*)(KbB + (size_t)(kb + 1) * 8192 + c * 4096 + tid * 16);
    }

    if (kb >= kbmax - 1){
      #pragma unroll
      for (int kt = 0; kt < 4; ++kt)
        #pragma unroll
        for (int r = 0; r < 4; ++r){
          const int key = k0 + kt * 16 + g * 4 + r;
          if (key > qA) sA[kt][r] = -INFINITY;
          if (key > qB) sB[kt][r] = -INFINITY;
        }
    }

    {
      float sum = 0.f;
      #pragma unroll
      for (int kt = 0; kt < 4; ++kt){
        #pragma unroll
        for (int r = 0; r < 4; ++r){
          const float pp = __builtin_amdgcn_exp2f(sA[kt][r]);
          sA[kt][r] = pp; sum += pp;
        }
        unsigned int p01, p23;
        asm("v_cvt_pk_bf16_f32 %0, %1, %2" : "=v"(p01) : "v"(sA[kt][0]), "v"(sA[kt][1]));
        asm("v_cvt_pk_bf16_f32 %0, %1, %2" : "=v"(p23) : "v"(sA[kt][2]), "v"(sA[kt][3]));
        uint2 pk; pk.x = p01; pk.y = p23;
        *(uint2*)(PbA + lr * 128 + ((kt * 32 + g * 8) ^ swzl)) = pk;
      }
      sum += __shfl_xor(sum, 16);
      sum += __shfl_xor(sum, 32);
      lA += sum;
    }
    {
      float sum = 0.f;
      #pragma unroll
      for (int kt = 0; kt < 4; ++kt){
        #pragma unroll
        for (int r = 0; r < 4; ++r){
          const float pp = __builtin_amdgcn_exp2f(sB[kt][r]);
          sB[kt][r] = pp; sum += pp;
        }
        unsigned int p01, p23;
        asm("v_cvt_pk_bf16_f32 %0, %1, %2" : "=v"(p01) : "v"(sB[kt][0]), "v"(sB[kt][1]));
        asm("v_cvt_pk_bf16_f32 %0, %1, %2" : "=v"(p23) : "v"(sB[kt][2]), "v"(sB[kt][3]));
        uint2 pk; pk.x = p01; pk.y = p23;
        *(uint2*)(PbB + lr * 128 + ((kt * 32 + g * 8) ^ swzl)) = pk;
      }
      sum += __shfl_xor(sum, 16);
      sum += __shfl_xor(sum, 32);
      lB += sum;
    }

    const short8 paA0 = *(const short8*)(PbA + lr * 128 + ((g * 16) ^ swzl));
    const short8 paA1 = *(const short8*)(PbA + lr * 128 + ((64 + g * 16) ^ swzl));
    const short8 paB0 = *(const short8*)(PbB + lr * 128 + ((g * 16) ^ swzl));
    const short8 paB1 = *(const short8*)(PbB + lr * 128 + ((64 + g * 16) ^ swzl));
    __builtin_amdgcn_s_setprio(1);
    #pragma unroll
    for (int dt = 0; dt < 4; ++dt){
      oA[dt] = __builtin_amdgcn_mfma_f32_16x16x32_bf16(paA0, vf[dt][0], oA[dt], 0, 0, 0);
      oA[dt] = __builtin_amdgcn_mfma_f32_16x16x32_bf16(paA1, vf[dt][1], oA[dt], 0, 0, 0);
      oB[dt] = __builtin_amdgcn_mfma_f32_16x16x32_bf16(paB0, vf[dt][0], oB[dt], 0, 0, 0);
      oB[dt] = __builtin_amdgcn_mfma_f32_16x16x32_bf16(paB1, vf[dt][1], oB[dt], 0, 0, 0);
    }
    __builtin_amdgcn_s_setprio(0);
  }

  const int b = bh >> 4, hh = bh & 15;
  {
    float lv[4];
    #pragma unroll
    for (int r = 0; r < 4; ++r) lv[r] = __shfl(lA, g * 4 + r);
    #pragma unroll
    for (int dt = 0; dt < 4; ++dt)
      #pragma unroll
      for (int r = 0; r < 4; ++r)
        Op[((size_t)(b * SEQ) + q0w + g * 4 + r) * D_MODEL + hh * 64 + dt * 16 + lr] = oA[dt][r] / lv[r];
  }
  {
    float lv[4];
    #pragma unroll
    for (int r = 0; r < 4; ++r) lv[r] = __shfl(lB, g * 4 + r);
    #pragma unroll
    for (int dt = 0; dt < 4; ++dt)
      #pragma unroll
      for (int r = 0; r < 4; ++r)
        Op[((size_t)(b * SEQ) + q0w + 16 + g * 4 + r) * D_MODEL + hh * 64 + dt * 16 + lr] = oB[dt][r] / lv[r];
  }
}

// ---------------- fused residual(+partials)(+bias) + layernorm ----------------
__global__ __launch_bounds__(256) void ln_kernel(const float* __restrict__ Af32,
                                                 const unsigned short* __restrict__ Abf,
                                                 const float* __restrict__ B1,
                                                 const unsigned short* __restrict__ P4,
                                                 size_t pstride,
                                                 const float* __restrict__ bias,
                                                 const float* __restrict__ g,
                                                 const float* __restrict__ be,
                                                 float* __restrict__ outF,
                                                 unsigned short* __restrict__ outH){
  const int row = blockIdx.x, tid = threadIdx.x;
  const size_t base = (size_t)row * D_MODEL + tid * 4;
  float v0, v1, v2, v3;
  if (Af32){
    float4 va = *(const float4*)(Af32 + base);
    v0 = va.x; v1 = va.y; v2 = va.z; v3 = va.w;
  } else {
    us4 ua = *(const us4*)(Abf + base);
    v0 = bf2f(ua[0]); v1 = bf2f(ua[1]); v2 = bf2f(ua[2]); v3 = bf2f(ua[3]);
  }
  if (B1){
    float4 vb = *(const float4*)(B1 + base);
    v0 += vb.x; v1 += vb.y; v2 += vb.z; v3 += vb.w;
  }
  if (P4){
    #pragma unroll
    for (int p = 0; p < 4; ++p){
      us4 u = *(const us4*)(P4 + p * pstride + base);
      v0 += bf2f(u[0]); v1 += bf2f(u[1]); v2 += bf2f(u[2]); v3 += bf2f(u[3]);
    }
  }
  if (bias){
    float4 vd = *(const float4*)(bias + tid * 4);
    v0 += vd.x; v1 += vd.y; v2 += vd.z; v3 += vd.w;
  }
  float s  = v0 + v1 + v2 + v3;
  float ss = v0*v0 + v1*v1 + v2*v2 + v3*v3;
  s = wave_sum(s); ss = wave_sum(ss);
  __shared__ float red[8];
  const int w = tid >> 6, lane = tid & 63;
  if (!lane){ red[w] = s; red[4 + w] = ss; }
  __syncthreads();
  s  = red[0] + red[1] + red[2] + red[3];
  ss = red[4] + red[5] + red[6] + red[7];
  const float mu  = s * (1.0f / D_MODEL);
  const float var = ss * (1.0f / D_MODEL) - mu * mu;
  const float rstd = rsqrtf(var + 1e-5f);
  float4 gg = *(const float4*)(g  + tid * 4);
  float4 bb = *(const float4*)(be + tid * 4);
  const float r0 = (v0 - mu) * rstd * gg.x + bb.x;
  const float r1 = (v1 - mu) * rstd * gg.y + bb.y;
  const float r2 = (v2 - mu) * rstd * gg.z + bb.z;
  const float r3 = (v3 - mu) * rstd * gg.w + bb.w;
  if (outF){
    float4 of; of.x = r0; of.y = r1; of.z = r2; of.w = r3;
    *(float4*)(outF + base) = of;
  }
  if (outH){
    us4 oh; oh[0] = f2bf(r0); oh[1] = f2bf(r1); oh[2] = f2bf(r2); oh[3] = f2bf(r3);
    *(us4*)(outH + base) = oh;
  }
}

extern "C" void kernel_launch(void* const* d_in, const int* in_sizes, int n_in,
                              void* d_out, int out_size, void* d_ws, size_t ws_size,
                              hipStream_t stream){
  (void)in_sizes; (void)n_in; (void)out_size;
  const float* x     = (const float*)d_in[0];
  const float* W_qkv = (const float*)d_in[1];
  const float* b_qkv = (const float*)d_in[2];
  const float* W1    = (const float*)d_in[3];
  const float* b1    = (const float*)d_in[4];
  const float* W2    = (const float*)d_in[5];
  const float* b2    = (const float*)d_in[6];
  const float* ln1g  = (const float*)d_in[7];
  const float* ln1b  = (const float*)d_in[8];
  const float* ln2g  = (const float*)d_in[9];
  const float* ln2b  = (const float*)d_in[10];

  char* ws = (char*)d_ws;
  const size_t MB = 1024ull * 1024ull;
  unsigned short* WqkvT = (unsigned short*)(ws + 0 * MB);
  unsigned short* W1T   = (unsigned short*)(ws + 6 * MB);
  unsigned short* W2T   = (unsigned short*)(ws + 14 * MB);
  unsigned short* xbf   = (unsigned short*)(ws + 22 * MB);
  unsigned short* qB    = (unsigned short*)(ws + 30 * MB);
  unsigned short* kB    = (unsigned short*)(ws + 39 * MB);
  unsigned short* vT    = (unsigned short*)(ws + 48 * MB);
  float* attn = (float*)(ws + 57 * MB);
  unsigned short* hB  = (unsigned short*)(ws + 46 * MB);   // bf16 h, LN1 -> FFN1 + LN2 residual
  unsigned short* ff1 = (unsigned short*)(ws + 54 * MB);
  unsigned short* pbf = (unsigned short*)(ws + 86 * MB);   // 4 x bf16 partial [4096][1024], 32MB
  float* p0           = (float*)(ws + 86 * MB);            // fallback f32 partial, 16MB

  const int use4b = (ws_size >= 118 * MB);

  // 1. preprocess
  cast_bf16_kernel<<<4096, 256, 0, stream>>>(x, xbf, ROWS * D_MODEL / 4);
  transpose_cast_kernel<<<dim3(96, 32), 256, 0, stream>>>(W_qkv, WqkvT, 1024, 3072);
  transpose_cast_kernel<<<dim3(128, 32), 256, 0, stream>>>(W1, W1T, 1024, 4096);
  transpose_cast_kernel<<<dim3(32, 128), 256, 0, stream>>>(W2, W2T, 4096, 1024);

  // 2. QKV projection (M=4096,N=3072,K=1024): v2 proven, grid 24*32=768
  gemm_kernel<0><<<768, 256, 0, stream>>>(
      xbf, WqkvT, b_qkv, ROWS, 3072, 1024, 1024, 24, 32, nullptr, qB, kB, vT);

  // 3. causal MFMA flash attention (exp2-domain, max-free, V direct-global)
  attn_mfma_kernel<<<512, 256, 0, stream>>>(qB, kB, vT, attn);

  // 4. h = LN(x + attn) -> bf16 only
  ln_kernel<<<ROWS, 256, 0, stream>>>(x, nullptr, attn, nullptr, 0, nullptr,
                                      ln1g, ln1b, nullptr, hB);

  // 5. ff1 = relu(h @ W1 + b1) (M=4096,N=4096,K=1024): gemm4b, grid 16*16=256
  gemm4b_kernel<1><<<256, 512, 0, stream>>>(
      hB, W1T, b1, ROWS, FFDIM, 1024, 1024, 16, 16, ff1);

  // 6+7. FFN2 + LN2 (residual rebuilt from bf16 h)
  if (use4b){
    gemm4b_kernel<4><<<256, 512, 0, stream>>>(
        ff1, W2T, nullptr, ROWS, 1024, FFDIM, 1024, 4, 16, pbf);
    ln_kernel<<<ROWS, 256, 0, stream>>>(nullptr, hB, nullptr, pbf, (size_t)ROWS * 1024, b2,
                                        ln2g, ln2b, (float*)d_out, nullptr);
  } else {
    gemm_kernel<3><<<256, 256, 0, stream>>>(
        ff1, W2T, nullptr, ROWS, 1024, FFDIM, FFDIM, 8, 32, p0, nullptr, nullptr, nullptr);
    ln_kernel<<<ROWS, 256, 0, stream>>>(nullptr, hB, p0, nullptr, 0, b2,
                                        ln2g, ln2b, (float*)d_out, nullptr);
  }
}

// Round 16
// 195.598 us; speedup vs baseline: 1.0580x; 1.0580x over previous
//
#include <hip/hip_runtime.h>

#define D_MODEL 1024
#define HEADS   16
#define HEAD_DIM 64
#define SEQ     2048
#define BATCH   2
#define ROWS    (BATCH*SEQ)   /* 4096 */
#define FFDIM   4096

typedef __attribute__((ext_vector_type(8))) short short8;
typedef __attribute__((ext_vector_type(4))) float f32x4;
typedef __attribute__((ext_vector_type(4))) unsigned short us4;

typedef const __attribute__((address_space(1))) unsigned int* gptr_t;
typedef __attribute__((address_space(3))) unsigned int* lptr_t;

__device__ __forceinline__ unsigned short f2bf(float f){
  unsigned int x = __float_as_uint(f);
  x += 0x7fffu + ((x >> 16) & 1u);
  return (unsigned short)(x >> 16);
}
__device__ __forceinline__ float bf2f(unsigned short u){
  return __uint_as_float((unsigned int)u << 16);
}

__device__ __forceinline__ float wave_sum(float x){
  #pragma unroll
  for (int off = 32; off; off >>= 1) x += __shfl_xor(x, off);
  return x;
}

// ---------------- cast fp32 -> bf16 (vectorized) ----------------
__global__ __launch_bounds__(256) void cast_bf16_kernel(const float* __restrict__ in,
                                                        unsigned short* __restrict__ out, int n4){
  int i = blockIdx.x * 256 + threadIdx.x;
  if (i >= n4) return;
  float4 v = *(const float4*)(in + (size_t)i * 4);
  us4 o;
  o[0] = f2bf(v.x); o[1] = f2bf(v.y); o[2] = f2bf(v.z); o[3] = f2bf(v.w);
  *(us4*)(out + (size_t)i * 4) = o;
}

// ---------------- transpose + cast: in [R][C] f32 -> out [C][R] bf16 ----------------
__global__ __launch_bounds__(256) void transpose_cast_kernel(const float* __restrict__ in,
                                                             unsigned short* __restrict__ out,
                                                             int R, int C){
  __shared__ float tile[32][33];
  const int bc = blockIdx.x * 32, br = blockIdx.y * 32;
  const int tx = threadIdx.x & 31, ty = threadIdx.x >> 5;  // ty 0..7
  #pragma unroll
  for (int j = 0; j < 4; ++j)
    tile[ty + 8*j][tx] = in[(size_t)(br + ty + 8*j) * C + bc + tx];
  __syncthreads();
  #pragma unroll
  for (int j = 0; j < 4; ++j)
    out[(size_t)(bc + ty + 8*j) * R + br + tx] = f2bf(tile[tx][ty + 8*j]);
}

// ---------------- bf16 MFMA GEMM v2 (proven): 2-phase dbuf, XCD-swizzled ----------------
// EPI 0: QKV epilogue -> q bf16 (scaled 0.125*log2e), k bf16, V^T bf16 [B,H,64,T]
// EPI 3: f32 partial (no bias) to outF + sk*M*N   (split-K fallback)
template<int EPI>
__global__ __launch_bounds__(256) void gemm_kernel(const unsigned short* __restrict__ A,
                                                   const unsigned short* __restrict__ BT,
                                                   const float* __restrict__ bias,
                                                   int M, int N, int K, int kchunk,
                                                   int gx, int gy,
                                                   float* __restrict__ outF,
                                                   unsigned short* __restrict__ qo,
                                                   unsigned short* __restrict__ ko,
                                                   unsigned short* __restrict__ vT){
  __shared__ __align__(16) unsigned short Alds[2][128 * 32];
  __shared__ __align__(16) unsigned short Blds[2][128 * 32];
  const int tid = threadIdx.x;
  const int lane = tid & 63;
  const int wid = tid >> 6;
  const int wr = wid >> 1, wc = wid & 1;
  const int lrow = lane & 15, lgrp = lane >> 4;

  const int nwg = gridDim.x;
  const int cpx = nwg >> 3;
  const int wg = (blockIdx.x & 7) * cpx + (blockIdx.x >> 3);
  const int nx = wg % gx;
  const int rest = wg / gx;
  const int my = rest % gy;
  const int sk = rest / gy;

  const int m0 = my * 128, n0 = nx * 128;
  const int kbase0 = sk * kchunk;
  const int sr = lane >> 2, sc = (lane & 3) * 8;

  f32x4 acc[4][4];
  #pragma unroll
  for (int i = 0; i < 4; ++i)
    #pragma unroll
    for (int j = 0; j < 4; ++j)
      acc[i][j] = f32x4{0.f, 0.f, 0.f, 0.f};

  #pragma unroll
  for (int it = 0; it < 2; ++it){
    const int c = wid * 2 + it;
    const int r = c * 16 + sr;
    __builtin_amdgcn_global_load_lds(
        (gptr_t)(const void*)(A + (size_t)(m0 + r) * K + kbase0 + sc),
        (lptr_t)(void*)(&Alds[0][c * 512]), 16, 0, 0);
    __builtin_amdgcn_global_load_lds(
        (gptr_t)(const void*)(BT + (size_t)(n0 + r) * K + kbase0 + sc),
        (lptr_t)(void*)(&Blds[0][c * 512]), 16, 0, 0);
  }

  const int nk = kchunk >> 5;
  int cur = 0;
  for (int kt = 0; kt < nk; ++kt){
    __syncthreads();
    if (kt + 1 < nk){
      const int kb = kbase0 + (kt + 1) * 32;
      #pragma unroll
      for (int it = 0; it < 2; ++it){
        const int c = wid * 2 + it;
        const int r = c * 16 + sr;
        __builtin_amdgcn_global_load_lds(
            (gptr_t)(const void*)(A + (size_t)(m0 + r) * K + kb + sc),
            (lptr_t)(void*)(&Alds[cur ^ 1][c * 512]), 16, 0, 0);
        __builtin_amdgcn_global_load_lds(
            (gptr_t)(const void*)(BT + (size_t)(n0 + r) * K + kb + sc),
            (lptr_t)(void*)(&Blds[cur ^ 1][c * 512]), 16, 0, 0);
      }
    }
    short8 af[4], bfr[4];
    #pragma unroll
    for (int f = 0; f < 4; ++f){
      af[f]  = *(const short8*)&Alds[cur][(wr * 64 + f * 16 + lrow) * 32 + lgrp * 8];
      bfr[f] = *(const short8*)&Blds[cur][(wc * 64 + f * 16 + lrow) * 32 + lgrp * 8];
    }
    __builtin_amdgcn_s_setprio(1);
    #pragma unroll
    for (int i = 0; i < 4; ++i)
      #pragma unroll
      for (int j = 0; j < 4; ++j)
        acc[i][j] = __builtin_amdgcn_mfma_f32_16x16x32_bf16(af[i], bfr[j], acc[i][j], 0, 0, 0);
    __builtin_amdgcn_s_setprio(0);
    cur ^= 1;
  }

  // epilogue: D row = (lane>>4)*4 + reg, col = lane&15 (m89-verified layout)
  #pragma unroll
  for (int i = 0; i < 4; ++i){
    const int rg = m0 + wr * 64 + i * 16 + lgrp * 4;
    #pragma unroll
    for (int j = 0; j < 4; ++j){
      const int cg = n0 + wc * 64 + j * 16 + lrow;
      if constexpr (EPI == 0){
        const float bb = bias[cg];
        const int which = cg >> 10, rem = cg & 1023;
        const int hh = rem >> 6, dd = rem & 63;
        const int bb_ = rg >> 11, tt = rg & 2047;
        const size_t bh = (size_t)(bb_ * HEADS + hh);
        if (which == 2){
          us4 pk;
          #pragma unroll
          for (int r = 0; r < 4; ++r) pk[r] = f2bf(acc[i][j][r] + bb);
          *(us4*)(vT + (bh * 64 + dd) * SEQ + tt) = pk;
        } else {
          unsigned short* dst = which ? ko : qo;
          const float sc2 = which ? 1.0f : 0.18033688f;  // q: (1/8)*log2e
          #pragma unroll
          for (int r = 0; r < 4; ++r)
            dst[(bh * SEQ + tt + r) * 64 + dd] = f2bf((acc[i][j][r] + bb) * sc2);
        }
      } else {
        float* outP = outF + (size_t)sk * M * N;
        #pragma unroll
        for (int r = 0; r < 4; ++r)
          outP[(size_t)(rg + r) * N + cg] = acc[i][j][r];
      }
    }
  }
}

// ================= 256x256 4-barrier-halved bf16 MFMA GEMM ("gemm4b", r14 proven) =================
template<int EPI>
__global__ __launch_bounds__(512, 1) void gemm4b_kernel(const unsigned short* __restrict__ A,
                                                        const unsigned short* __restrict__ BT,
                                                        const float* __restrict__ bias,
                                                        int M, int N, int K, int kchunk,
                                                        int gx, int gy,
                                                        unsigned short* __restrict__ outH){
  __shared__ __align__(16) unsigned short Ab[2][2][256 * 32];
  __shared__ __align__(16) unsigned short Bb[2][2][256 * 32];
  const int tid = threadIdx.x, lane = tid & 63, wid = tid >> 6;
  const int wm = wid >> 2, wn = wid & 3;
  const int lr = lane & 15, g = lane >> 4;

  const int nwg = gridDim.x, cpx = nwg >> 3;
  const int wg = (blockIdx.x & 7) * cpx + (blockIdx.x >> 3);
  const int nx = wg % gx;
  const int rest = wg / gx;
  const int my = rest % gy;
  const int sk = rest / gy;
  const int m0 = my * 256, n0 = nx * 256, kb0 = sk * kchunk;
  const int nk = kchunk >> 6;   // BK = 64

  f32x4 acc[8][4];
  #pragma unroll
  for (int i = 0; i < 8; ++i)
    #pragma unroll
    for (int j = 0; j < 4; ++j)
      acc[i][j] = f32x4{0.f, 0.f, 0.f, 0.f};

  auto STAGE = [&](int op, int t, int kh){
    const int d_ = t & 1;
    unsigned short* base = op ? &Bb[d_][kh][0] : &Ab[d_][kh][0];
    const unsigned short* src = op ? BT : A;
    const int r0 = op ? n0 : m0;
    #pragma unroll
    for (int j = 0; j < 2; ++j){
      const int L = tid + j * 512;
      const int row = L >> 2, c = L & 3;
      __builtin_amdgcn_global_load_lds(
          (gptr_t)(const void*)(src + (size_t)(r0 + row) * K + kb0 + t * 64 + kh * 32
                                + ((c ^ ((row >> 1) & 3)) << 3)),
          (lptr_t)(void*)(base + L * 8), 16, 0, 0);
    }
  };

  short8 afr[8], bfr[4];

  #define READS(d_, kh_)                                                                  \
    _Pragma("unroll")                                                                     \
    for (int i = 0; i < 8; ++i){                                                          \
      const int row = wm * 128 + i * 16 + lr;                                             \
      afr[i] = *(const short8*)&Ab[d_][kh_][row * 32 + ((g ^ ((row >> 1) & 3)) << 3)];    \
    }                                                                                     \
    _Pragma("unroll")                                                                     \
    for (int j = 0; j < 4; ++j){                                                          \
      const int row = wn * 64 + j * 16 + lr;                                              \
      bfr[j] = *(const short8*)&Bb[d_][kh_][row * 32 + ((g ^ ((row >> 1) & 3)) << 3)];    \
    }

  #define MFMA32()                                                                        \
    __builtin_amdgcn_sched_barrier(0);                                                    \
    __builtin_amdgcn_s_setprio(1);                                                        \
    _Pragma("unroll")                                                                     \
    for (int i = 0; i < 8; ++i)                                                           \
      _Pragma("unroll")                                                                   \
      for (int j = 0; j < 4; ++j)                                                         \
        acc[i][j] = __builtin_amdgcn_mfma_f32_16x16x32_bf16(afr[i], bfr[j], acc[i][j], 0, 0, 0); \
    __builtin_amdgcn_s_setprio(0);

  // prologue: stage (0,kh0), (0,kh1), (1,kh0)
  STAGE(0,0,0); STAGE(1,0,0); STAGE(0,0,1); STAGE(1,0,1);
  if (nk > 1){ STAGE(0,1,0); STAGE(1,1,0); }

  for (int t = 0; t < nk; ++t){
    const int d = t & 1;

    // ---- Phase A(t): consume (t,kh0) ----
    if (t + 1 < nk) asm volatile("s_waitcnt vmcnt(8)" ::: "memory");
    else            asm volatile("s_waitcnt vmcnt(4)" ::: "memory");
    __builtin_amdgcn_s_barrier();
    READS(d, 0)
    if (t + 1 < nk){ STAGE(0, t + 1, 1); STAGE(1, t + 1, 1); }
    asm volatile("s_waitcnt lgkmcnt(0)" ::: "memory");
    MFMA32()

    // ---- Phase B(t): consume (t,kh1) ----
    if (t + 1 < nk) asm volatile("s_waitcnt vmcnt(8)" ::: "memory");
    else            asm volatile("s_waitcnt vmcnt(0)" ::: "memory");
    __builtin_amdgcn_s_barrier();
    READS(d, 1)
    if (t + 2 < nk){ STAGE(0, t + 2, 0); STAGE(1, t + 2, 0); }
    asm volatile("s_waitcnt lgkmcnt(0)" ::: "memory");
    MFMA32()
  }
  #undef READS
  #undef MFMA32

  // ---- epilogue: D row = g*4 + reg, col = lr (m89-verified) ----
  #pragma unroll
  for (int i = 0; i < 8; ++i){
    const int rg = m0 + wm * 128 + i * 16 + g * 4;
    #pragma unroll
    for (int j = 0; j < 4; ++j){
      const int cg = n0 + wn * 64 + j * 16 + lr;
      if constexpr (EPI == 1){
        const float bb = bias[cg];
        #pragma unroll
        for (int r = 0; r < 4; ++r)
          outH[(size_t)(rg + r) * N + cg] = f2bf(fmaxf(acc[i][j][r] + bb, 0.f));
      } else {
        unsigned short* dst = outH + (size_t)sk * M * N;
        #pragma unroll
        for (int r = 0; r < 4; ++r)
          dst[(size_t)(rg + r) * N + cg] = f2bf(acc[i][j][r]);
      }
    }
  }
}

// ---------------- MFMA flash attention v3 (r14 proven): K+V LDS dbuf, exp2, max-free ----------
__global__ __launch_bounds__(256) void attn_mfma_kernel(const unsigned short* __restrict__ Qb,
                                                        const unsigned short* __restrict__ Kb,
                                                        const unsigned short* __restrict__ VT,
                                                        float* __restrict__ Op){
  __shared__ __align__(16) char Kl[2][8192];
  __shared__ __align__(16) char Vl[2][8192];
  __shared__ __align__(16) char Pl[4][4096];
  const int tid = threadIdx.x;
  const int w = tid >> 6, lane = tid & 63;
  const int lr = lane & 15, g = lane >> 4;

  const int bx = blockIdx.x, u = bx & 255, half = bx >> 8;
  const int g8 = u >> 5;
  const int qg = half ? g8 : 15 - g8;
  const int bh = u & 31;

  const int q0w = qg * 128 + w * 32;
  const int qA = q0w + lr, qB = qA + 16;

  const char* const KbB = (const char*)(Kb + (size_t)bh * SEQ * 64);
  const char* const VbB = (const char*)(VT + (size_t)bh * 64 * SEQ);
  char* const PbA = Pl[w];
  char* const PbB = Pl[w] + 2048;

  const unsigned short* qra = Qb + ((size_t)bh * SEQ + qA) * 64 + g * 8;
  const short8 qfA0 = *(const short8*)(qra);
  const short8 qfA1 = *(const short8*)(qra + 32);
  const short8 qfB0 = *(const short8*)(qra + 16 * 64);
  const short8 qfB1 = *(const short8*)(qra + 16 * 64 + 32);

  f32x4 oA[4], oB[4];
  #pragma unroll
  for (int dt = 0; dt < 4; ++dt){ oA[dt] = f32x4{0.f,0.f,0.f,0.f}; oB[dt] = f32x4{0.f,0.f,0.f,0.f}; }
  float lA = 0.f, lB = 0.f;
  const int swzl = (lr & 7) << 4;

  const int kbmax = 2 * qg + 1;

  short8 st[4];
  {
    #pragma unroll
    for (int c = 0; c < 2; ++c){
      const int L = c * 4096 + tid * 16;
      st[c] = *(const short8*)(KbB + L);
      const int row = L >> 7, col = L & 127;
      st[2 + c] = *(const short8*)(VbB + (size_t)row * 4096 + col);
    }
  }

  for (int kb = 0; kb <= kbmax; ++kb){
    const int p = kb & 1;
    const int k0 = kb * 64;

    #pragma unroll
    for (int c = 0; c < 2; ++c){
      const int L = c * 4096 + tid * 16;
      const int row = L >> 7, col = L & 127;
      const int dst = row * 128 + (col ^ ((row & 7) << 4));
      *(short8*)(Kl[p] + dst) = st[c];
      *(short8*)(Vl[p] + dst) = st[2 + c];
    }
    __syncthreads();

    if (kb < kbmax){
      #pragma unroll
      for (int c = 0; c < 2; ++c){
        const int L = c * 4096 + tid * 16;
        st[c] = *(const short8*)(KbB + (size_t)(kb + 1) * 8192 + L);
        const int row = L >> 7, col = L & 127;
        st[2 + c] = *(const short8*)(VbB + (size_t)row * 4096 + (size_t)(kb + 1) * 128 + col);
      }
    }

    f32x4 sA[4], sB[4];
    __builtin_amdgcn_s_setprio(1);
    #pragma unroll
    for (int kt = 0; kt < 4; ++kt){
      const int row = kt * 16 + lr;
      const int ro = row * 128, sw = (row & 7) << 4;
      const short8 kf0 = *(const short8*)(Kl[p] + ro + ((g * 16) ^ sw));
      const short8 kf1 = *(const short8*)(Kl[p] + ro + ((64 + g * 16) ^ sw));
      sA[kt] = __builtin_amdgcn_mfma_f32_16x16x32_bf16(kf0, qfA0, f32x4{0.f,0.f,0.f,0.f}, 0, 0, 0);
      sA[kt] = __builtin_amdgcn_mfma_f32_16x16x32_bf16(kf1, qfA1, sA[kt], 0, 0, 0);
      sB[kt] = __builtin_amdgcn_mfma_f32_16x16x32_bf16(kf0, qfB0, f32x4{0.f,0.f,0.f,0.f}, 0, 0, 0);
      sB[kt] = __builtin_amdgcn_mfma_f32_16x16x32_bf16(kf1, qfB1, sB[kt], 0, 0, 0);
    }
    __builtin_amdgcn_s_setprio(0);

    if (kb >= kbmax - 1){
      #pragma unroll
      for (int kt = 0; kt < 4; ++kt)
        #pragma unroll
        for (int r = 0; r < 4; ++r){
          const int key = k0 + kt * 16 + g * 4 + r;
          if (key > qA) sA[kt][r] = -INFINITY;
          if (key > qB) sB[kt][r] = -INFINITY;
        }
    }

    {
      float sum = 0.f;
      #pragma unroll
      for (int kt = 0; kt < 4; ++kt){
        #pragma unroll
        for (int r = 0; r < 4; ++r){
          const float pp = __builtin_amdgcn_exp2f(sA[kt][r]);
          sA[kt][r] = pp; sum += pp;
        }
        unsigned int p01, p23;
        asm("v_cvt_pk_bf16_f32 %0, %1, %2" : "=v"(p01) : "v"(sA[kt][0]), "v"(sA[kt][1]));
        asm("v_cvt_pk_bf16_f32 %0, %1, %2" : "=v"(p23) : "v"(sA[kt][2]), "v"(sA[kt][3]));
        uint2 pk; pk.x = p01; pk.y = p23;
        *(uint2*)(PbA + lr * 128 + ((kt * 32 + g * 8) ^ swzl)) = pk;
      }
      sum += __shfl_xor(sum, 16);
      sum += __shfl_xor(sum, 32);
      lA += sum;
    }
    {
      float sum = 0.f;
      #pragma unroll
      for (int kt = 0; kt < 4; ++kt){
        #pragma unroll
        for (int r = 0; r < 4; ++r){
          const float pp = __builtin_amdgcn_exp2f(sB[kt][r]);
          sB[kt][r] = pp; sum += pp;
        }
        unsigned int p01, p23;
        asm("v_cvt_pk_bf16_f32 %0, %1, %2" : "=v"(p01) : "v"(sB[kt][0]), "v"(sB[kt][1]));
        asm("v_cvt_pk_bf16_f32 %0, %1, %2" : "=v"(p23) : "v"(sB[kt][2]), "v"(sB[kt][3]));
        uint2 pk; pk.x = p01; pk.y = p23;
        *(uint2*)(PbB + lr * 128 + ((kt * 32 + g * 8) ^ swzl)) = pk;
      }
      sum += __shfl_xor(sum, 16);
      sum += __shfl_xor(sum, 32);
      lB += sum;
    }

    const short8 paA0 = *(const short8*)(PbA + lr * 128 + ((g * 16) ^ swzl));
    const short8 paA1 = *(const short8*)(PbA + lr * 128 + ((64 + g * 16) ^ swzl));
    const short8 paB0 = *(const short8*)(PbB + lr * 128 + ((g * 16) ^ swzl));
    const short8 paB1 = *(const short8*)(PbB + lr * 128 + ((64 + g * 16) ^ swzl));
    __builtin_amdgcn_s_setprio(1);
    #pragma unroll
    for (int dt = 0; dt < 4; ++dt){
      const int row = dt * 16 + lr;
      const int ro = row * 128, sw = (row & 7) << 4;
      const short8 vf0 = *(const short8*)(Vl[p] + ro + ((g * 16) ^ sw));
      const short8 vf1 = *(const short8*)(Vl[p] + ro + ((64 + g * 16) ^ sw));
      oA[dt] = __builtin_amdgcn_mfma_f32_16x16x32_bf16(paA0, vf0, oA[dt], 0, 0, 0);
      oA[dt] = __builtin_amdgcn_mfma_f32_16x16x32_bf16(paA1, vf1, oA[dt], 0, 0, 0);
      oB[dt] = __builtin_amdgcn_mfma_f32_16x16x32_bf16(paB0, vf0, oB[dt], 0, 0, 0);
      oB[dt] = __builtin_amdgcn_mfma_f32_16x16x32_bf16(paB1, vf1, oB[dt], 0, 0, 0);
    }
    __builtin_amdgcn_s_setprio(0);
  }

  const int b = bh >> 4, hh = bh & 15;
  {
    float lv[4];
    #pragma unroll
    for (int r = 0; r < 4; ++r) lv[r] = __shfl(lA, g * 4 + r);
    #pragma unroll
    for (int dt = 0; dt < 4; ++dt)
      #pragma unroll
      for (int r = 0; r < 4; ++r)
        Op[((size_t)(b * SEQ) + q0w + g * 4 + r) * D_MODEL + hh * 64 + dt * 16 + lr] = oA[dt][r] / lv[r];
  }
  {
    float lv[4];
    #pragma unroll
    for (int r = 0; r < 4; ++r) lv[r] = __shfl(lB, g * 4 + r);
    #pragma unroll
    for (int dt = 0; dt < 4; ++dt)
      #pragma unroll
      for (int r = 0; r < 4; ++r)
        Op[((size_t)(b * SEQ) + q0w + 16 + g * 4 + r) * D_MODEL + hh * 64 + dt * 16 + lr] = oB[dt][r] / lv[r];
  }
}

// ---------------- fused residual(+partials)(+bias) + layernorm ----------------
__global__ __launch_bounds__(256) void ln_kernel(const float* __restrict__ Af32,
                                                 const unsigned short* __restrict__ Abf,
                                                 const float* __restrict__ B1,
                                                 const unsigned short* __restrict__ P4,
                                                 size_t pstride,
                                                 const float* __restrict__ bias,
                                                 const float* __restrict__ g,
                                                 const float* __restrict__ be,
                                                 float* __restrict__ outF,
                                                 unsigned short* __restrict__ outH){
  const int row = blockIdx.x, tid = threadIdx.x;
  const size_t base = (size_t)row * D_MODEL + tid * 4;
  float v0, v1, v2, v3;
  if (Af32){
    float4 va = *(const float4*)(Af32 + base);
    v0 = va.x; v1 = va.y; v2 = va.z; v3 = va.w;
  } else {
    us4 ua = *(const us4*)(Abf + base);
    v0 = bf2f(ua[0]); v1 = bf2f(ua[1]); v2 = bf2f(ua[2]); v3 = bf2f(ua[3]);
  }
  if (B1){
    float4 vb = *(const float4*)(B1 + base);
    v0 += vb.x; v1 += vb.y; v2 += vb.z; v3 += vb.w;
  }
  if (P4){
    #pragma unroll
    for (int p = 0; p < 4; ++p){
      us4 u = *(const us4*)(P4 + p * pstride + base);
      v0 += bf2f(u[0]); v1 += bf2f(u[1]); v2 += bf2f(u[2]); v3 += bf2f(u[3]);
    }
  }
  if (bias){
    float4 vd = *(const float4*)(bias + tid * 4);
    v0 += vd.x; v1 += vd.y; v2 += vd.z; v3 += vd.w;
  }
  float s  = v0 + v1 + v2 + v3;
  float ss = v0*v0 + v1*v1 + v2*v2 + v3*v3;
  s = wave_sum(s); ss = wave_sum(ss);
  __shared__ float red[8];
  const int w = tid >> 6, lane = tid & 63;
  if (!lane){ red[w] = s; red[4 + w] = ss; }
  __syncthreads();
  s  = red[0] + red[1] + red[2] + red[3];
  ss = red[4] + red[5] + red[6] + red[7];
  const float mu  = s * (1.0f / D_MODEL);
  const float var = ss * (1.0f / D_MODEL) - mu * mu;
  const float rstd = rsqrtf(var + 1e-5f);
  float4 gg = *(const float4*)(g  + tid * 4);
  float4 bb = *(const float4*)(be + tid * 4);
  const float r0 = (v0 - mu) * rstd * gg.x + bb.x;
  const float r1 = (v1 - mu) * rstd * gg.y + bb.y;
  const float r2 = (v2 - mu) * rstd * gg.z + bb.z;
  const float r3 = (v3 - mu) * rstd * gg.w + bb.w;
  if (outF){
    float4 of; of.x = r0; of.y = r1; of.z = r2; of.w = r3;
    *(float4*)(outF + base) = of;
  }
  if (outH){
    us4 oh; oh[0] = f2bf(r0); oh[1] = f2bf(r1); oh[2] = f2bf(r2); oh[3] = f2bf(r3);
    *(us4*)(outH + base) = oh;
  }
}

extern "C" void kernel_launch(void* const* d_in, const int* in_sizes, int n_in,
                              void* d_out, int out_size, void* d_ws, size_t ws_size,
                              hipStream_t stream){
  (void)in_sizes; (void)n_in; (void)out_size;
  const float* x     = (const float*)d_in[0];
  const float* W_qkv = (const float*)d_in[1];
  const float* b_qkv = (const float*)d_in[2];
  const float* W1    = (const float*)d_in[3];
  const float* b1    = (const float*)d_in[4];
  const float* W2    = (const float*)d_in[5];
  const float* b2    = (const float*)d_in[6];
  const float* ln1g  = (const float*)d_in[7];
  const float* ln1b  = (const float*)d_in[8];
  const float* ln2g  = (const float*)d_in[9];
  const float* ln2b  = (const float*)d_in[10];

  char* ws = (char*)d_ws;
  const size_t MB = 1024ull * 1024ull;
  unsigned short* WqkvT = (unsigned short*)(ws + 0 * MB);
  unsigned short* W1T   = (unsigned short*)(ws + 6 * MB);
  unsigned short* W2T   = (unsigned short*)(ws + 14 * MB);
  unsigned short* xbf   = (unsigned short*)(ws + 22 * MB);
  unsigned short* qB    = (unsigned short*)(ws + 30 * MB);
  unsigned short* kB    = (unsigned short*)(ws + 39 * MB);
  unsigned short* vT    = (unsigned short*)(ws + 48 * MB);
  float* attn = (float*)(ws + 57 * MB);
  unsigned short* hB  = (unsigned short*)(ws + 46 * MB);   // bf16 h, LN1 -> FFN1 + LN2 residual
  unsigned short* ff1 = (unsigned short*)(ws + 54 * MB);
  unsigned short* pbf = (unsigned short*)(ws + 86 * MB);   // 4 x bf16 partial [4096][1024], 32MB
  float* p0           = (float*)(ws + 86 * MB);            // fallback f32 partial, 16MB

  const int use4b = (ws_size >= 118 * MB);

  // 1. preprocess
  cast_bf16_kernel<<<4096, 256, 0, stream>>>(x, xbf, ROWS * D_MODEL / 4);
  transpose_cast_kernel<<<dim3(96, 32), 256, 0, stream>>>(W_qkv, WqkvT, 1024, 3072);
  transpose_cast_kernel<<<dim3(128, 32), 256, 0, stream>>>(W1, W1T, 1024, 4096);
  transpose_cast_kernel<<<dim3(32, 128), 256, 0, stream>>>(W2, W2T, 4096, 1024);

  // 2. QKV projection (M=4096,N=3072,K=1024): v2 proven, grid 24*32=768
  gemm_kernel<0><<<768, 256, 0, stream>>>(
      xbf, WqkvT, b_qkv, ROWS, 3072, 1024, 1024, 24, 32, nullptr, qB, kB, vT);

  // 3. causal MFMA flash attention (exp2-domain, max-free, K+V LDS dbuf)
  attn_mfma_kernel<<<512, 256, 0, stream>>>(qB, kB, vT, attn);

  // 4. h = LN(x + attn) -> bf16 only
  ln_kernel<<<ROWS, 256, 0, stream>>>(x, nullptr, attn, nullptr, 0, nullptr,
                                      ln1g, ln1b, nullptr, hB);

  // 5. ff1 = relu(h @ W1 + b1) (M=4096,N=4096,K=1024): gemm4b, grid 16*16=256
  gemm4b_kernel<1><<<256, 512, 0, stream>>>(
      hB, W1T, b1, ROWS, FFDIM, 1024, 1024, 16, 16, ff1);

  // 6+7. FFN2 + LN2 (residual rebuilt from bf16 h)
  if (use4b){
    gemm4b_kernel<4><<<256, 512, 0, stream>>>(
        ff1, W2T, nullptr, ROWS, 1024, FFDIM, 1024, 4, 16, pbf);
    ln_kernel<<<ROWS, 256, 0, stream>>>(nullptr, hB, nullptr, pbf, (size_t)ROWS * 1024, b2,
                                        ln2g, ln2b, (float*)d_out, nullptr);
  } else {
    gemm_kernel<3><<<256, 256, 0, stream>>>(
        ff1, W2T, nullptr, ROWS, 1024, FFDIM, FFDIM, 8, 32, p0, nullptr, nullptr, nullptr);
    ln_kernel<<<ROWS, 256, 0, stream>>>(nullptr, hB, p0, nullptr, 0, b2,
                                        ln2g, ln2b, (float*)d_out, nullptr);
  }
}